// Round 1
// baseline (1003.896 us; speedup 1.0000x reference)
//
#include <hip/hip_runtime.h>
#include <math.h>

#define B_  2
#define S_  2048
#define H_  1024
#define NH_ 16
#define HD_ 64
#define M_  (B_*S_)   // 4096

// ---------------------------------------------------------------------------
// SGEMM: C = (X @ W + bias) * scale
// X: [M,1024] row-major, W: [1024,1024] row-major.
// SPLIT=1: out is [B][NH][S][HD] (head-split). SPLIT=0: out is [M][1024].
// Tile 128x128xBK8, 256 threads, 8x8 micro-tile (split 4+4 rows/cols).
// ---------------------------------------------------------------------------
template<int SPLIT>
__global__ __launch_bounds__(256)
void sgemm_kernel(const float* __restrict__ X, const float* __restrict__ W,
                  const float* __restrict__ bias, float* __restrict__ out,
                  float scale)
{
    const int tid = threadIdx.x;
    const int n0 = blockIdx.x * 128;   // grid.x = 8
    const int m0 = blockIdx.y * 128;   // grid.y = 32

    __shared__ float As[8][132];   // As[k][m] (transposed A tile)
    __shared__ float Bs[8][132];   // Bs[k][n]

    const int tx = tid & 15;       // col group
    const int ty = tid >> 4;       // row group

    // global-load assignments
    const int ar = tid >> 1;           // 0..127  (row within tile)
    const int ak = (tid & 1) * 4;      // 0 or 4  (k within tile)
    const int bk = tid >> 5;           // 0..7
    const int bc = (tid & 31) * 4;     // 0..124

    const float* Arow = X + (size_t)(m0 + ar) * 1024 + ak;
    const float* Bcol = W + (size_t)bk * 1024 + n0 + bc;

    float acc[8][8];
    #pragma unroll
    for (int i = 0; i < 8; i++)
        #pragma unroll
        for (int j = 0; j < 8; j++) acc[i][j] = 0.f;

    float4 aReg = *(const float4*)(Arow);
    float4 bReg = *(const float4*)(Bcol);

    for (int k0 = 0; k0 < 1024; k0 += 8) {
        As[ak + 0][ar] = aReg.x;
        As[ak + 1][ar] = aReg.y;
        As[ak + 2][ar] = aReg.z;
        As[ak + 3][ar] = aReg.w;
        *(float4*)&Bs[bk][bc] = bReg;
        __syncthreads();

        if (k0 + 8 < 1024) {
            aReg = *(const float4*)(Arow + k0 + 8);
            bReg = *(const float4*)(Bcol + (size_t)(k0 + 8) * 1024);
        }

        #pragma unroll
        for (int kk = 0; kk < 8; kk++) {
            float4 a0 = *(float4*)&As[kk][ty * 4];
            float4 a1 = *(float4*)&As[kk][64 + ty * 4];
            float4 b0 = *(float4*)&Bs[kk][tx * 4];
            float4 b1 = *(float4*)&Bs[kk][64 + tx * 4];
            float a[8] = {a0.x, a0.y, a0.z, a0.w, a1.x, a1.y, a1.z, a1.w};
            float b[8] = {b0.x, b0.y, b0.z, b0.w, b1.x, b1.y, b1.z, b1.w};
            #pragma unroll
            for (int i = 0; i < 8; i++)
                #pragma unroll
                for (int j = 0; j < 8; j++)
                    acc[i][j] += a[i] * b[j];
        }
        __syncthreads();
    }

    // epilogue
    #pragma unroll
    for (int i = 0; i < 8; i++) {
        const int mrow = m0 + ((i < 4) ? (ty * 4 + i) : (64 + ty * 4 + i - 4));
        const int bidx = mrow >> 11;         // / S_
        const int srow = mrow & (S_ - 1);
        #pragma unroll
        for (int jb = 0; jb < 2; jb++) {
            const int ncol = n0 + jb * 64 + tx * 4;
            float4 r;
            r.x = (acc[i][jb * 4 + 0] + bias[ncol + 0]) * scale;
            r.y = (acc[i][jb * 4 + 1] + bias[ncol + 1]) * scale;
            r.z = (acc[i][jb * 4 + 2] + bias[ncol + 2]) * scale;
            r.w = (acc[i][jb * 4 + 3] + bias[ncol + 3]) * scale;
            if (SPLIT) {
                const int nh = ncol >> 6;        // / HD_
                const int hd = ncol & (HD_ - 1);
                size_t idx = ((((size_t)bidx * NH_ + nh) * S_ + srow) * HD_) + hd;
                *(float4*)(out + idx) = r;
            } else {
                *(float4*)(out + (size_t)mrow * 1024 + ncol) = r;
            }
        }
    }
}

// ---------------------------------------------------------------------------
// Flash attention fp32. Block: (q-tile of 64 rows, head, batch). 256 threads.
// qh/kh/vh: [B][NH][S][HD]. mask: [B][S][S]. ao: [B][S][H] (merged heads).
// q is pre-scaled by 1/sqrt(HD).
// ---------------------------------------------------------------------------
__global__ __launch_bounds__(256)
void attn_kernel(const float* __restrict__ qh, const float* __restrict__ kh,
                 const float* __restrict__ vh, const float* __restrict__ mask,
                 float* __restrict__ ao)
{
    const int qt = blockIdx.x;     // 0..31
    const int h  = blockIdx.y;     // 0..15
    const int b  = blockIdx.z;     // 0..1

    __shared__ float Qt[64][68];   // Qt[d][r]
    __shared__ float Kt[64][68];   // Kt[d][j]
    __shared__ float Vs[64][68];   // Vs[j][d]
    __shared__ float St[64][68];   // St[j][r]  (P transposed)

    const int tid = threadIdx.x;
    const int g  = tid >> 4;       // 0..15 -> row group
    const int x  = tid & 15;       // 0..15 -> col/dim group
    const int r0 = g * 4;
    const int c0 = x * 4;

    const size_t headoff = ((size_t)b * NH_ + h) * S_ * HD_;
    const float* Qb = qh + headoff + (size_t)qt * 64 * HD_;
    const float* Kb = kh + headoff;
    const float* Vb = vh + headoff;
    const float* Mb = mask + (size_t)b * S_ * S_ + (size_t)qt * 64 * S_;

    // stage Q transposed (once)
    {
        const int jr = tid >> 2;            // 0..63
        const int dc = (tid & 3) * 16;      // 0,16,32,48
        const float* src = Qb + (size_t)jr * HD_ + dc;
        #pragma unroll
        for (int u = 0; u < 4; u++) {
            float4 tv = *(const float4*)(src + 4 * u);
            Qt[dc + 4 * u + 0][jr] = tv.x;
            Qt[dc + 4 * u + 1][jr] = tv.y;
            Qt[dc + 4 * u + 2][jr] = tv.z;
            Qt[dc + 4 * u + 3][jr] = tv.w;
        }
    }

    float acc[4][4];
    float m_run[4], l_run[4];
    #pragma unroll
    for (int i = 0; i < 4; i++) {
        m_run[i] = -3.0e38f;
        l_run[i] = 0.f;
        #pragma unroll
        for (int d = 0; d < 4; d++) acc[i][d] = 0.f;
    }

    for (int t = 0; t < S_ / 64; t++) {
        const int kbase = t * 64;
        // stage K transposed + V natural
        {
            const int jr = tid >> 2;
            const int dc = (tid & 3) * 16;
            const float* ksrc = Kb + (size_t)(kbase + jr) * HD_ + dc;
            #pragma unroll
            for (int u = 0; u < 4; u++) {
                float4 tv = *(const float4*)(ksrc + 4 * u);
                Kt[dc + 4 * u + 0][jr] = tv.x;
                Kt[dc + 4 * u + 1][jr] = tv.y;
                Kt[dc + 4 * u + 2][jr] = tv.z;
                Kt[dc + 4 * u + 3][jr] = tv.w;
            }
            const float* vsrc = Vb + (size_t)(kbase + jr) * HD_ + dc;
            #pragma unroll
            for (int u = 0; u < 4; u++) {
                float4 tv = *(const float4*)(vsrc + 4 * u);
                *(float4*)&Vs[jr][dc + 4 * u] = tv;
            }
        }
        __syncthreads();

        // scores: s[i][j] = sum_d Q[r0+i][d] * K[kbase+c0+j][d]
        float s[4][4];
        #pragma unroll
        for (int i = 0; i < 4; i++)
            #pragma unroll
            for (int j = 0; j < 4; j++) s[i][j] = 0.f;

        for (int d = 0; d < 64; d++) {
            float4 qv = *(float4*)&Qt[d][r0];
            float4 kv = *(float4*)&Kt[d][c0];
            float qa[4] = {qv.x, qv.y, qv.z, qv.w};
            float ka[4] = {kv.x, kv.y, kv.z, kv.w};
            #pragma unroll
            for (int i = 0; i < 4; i++)
                #pragma unroll
                for (int j = 0; j < 4; j++)
                    s[i][j] += qa[i] * ka[j];
        }

        // add mask
        #pragma unroll
        for (int i = 0; i < 4; i++) {
            float4 mv = *(const float4*)(Mb + (size_t)(r0 + i) * S_ + kbase + c0);
            s[i][0] += mv.x; s[i][1] += mv.y; s[i][2] += mv.z; s[i][3] += mv.w;
        }

        // online softmax (row reductions across the 16 lanes sharing g)
        #pragma unroll
        for (int i = 0; i < 4; i++) {
            float mx = fmaxf(fmaxf(s[i][0], s[i][1]), fmaxf(s[i][2], s[i][3]));
            #pragma unroll
            for (int off = 1; off < 16; off <<= 1)
                mx = fmaxf(mx, __shfl_xor(mx, off, 64));
            float mnew = fmaxf(m_run[i], mx);
            float corr = __expf(m_run[i] - mnew);
            float psum = 0.f;
            #pragma unroll
            for (int j = 0; j < 4; j++) {
                float p = __expf(s[i][j] - mnew);
                s[i][j] = p;
                psum += p;
            }
            #pragma unroll
            for (int off = 1; off < 16; off <<= 1)
                psum += __shfl_xor(psum, off, 64);
            l_run[i] = l_run[i] * corr + psum;
            m_run[i] = mnew;
            #pragma unroll
            for (int d = 0; d < 4; d++) acc[i][d] *= corr;
        }

        // write P transposed: St[c0+j][r0..r0+3]
        #pragma unroll
        for (int j = 0; j < 4; j++) {
            float4 pv = {s[0][j], s[1][j], s[2][j], s[3][j]};
            *(float4*)&St[c0 + j][r0] = pv;
        }
        __syncthreads();

        // PV: acc[i][d] += sum_j P[r0+i][j] * V[kbase+j][c0+d]
        for (int j = 0; j < 64; j++) {
            float4 pv = *(float4*)&St[j][r0];
            float4 vv = *(float4*)&Vs[j][c0];
            float pa[4] = {pv.x, pv.y, pv.z, pv.w};
            float va[4] = {vv.x, vv.y, vv.z, vv.w};
            #pragma unroll
            for (int i = 0; i < 4; i++)
                #pragma unroll
                for (int d = 0; d < 4; d++)
                    acc[i][d] += pa[i] * va[d];
        }
        __syncthreads();
    }

    // epilogue: divide by l, write to merged [B][S][H]
    #pragma unroll
    for (int i = 0; i < 4; i++) {
        const float inv = 1.0f / l_run[i];
        const int qrow = qt * 64 + r0 + i;
        float4 r;
        r.x = acc[i][0] * inv;
        r.y = acc[i][1] * inv;
        r.z = acc[i][2] * inv;
        r.w = acc[i][3] * inv;
        size_t idx = ((size_t)b * S_ + qrow) * H_ + h * HD_ + c0;
        *(float4*)(ao + idx) = r;
    }
}

// ---------------------------------------------------------------------------
extern "C" void kernel_launch(void* const* d_in, const int* in_sizes, int n_in,
                              void* d_out, int out_size, void* d_ws, size_t ws_size,
                              hipStream_t stream)
{
    (void)in_sizes; (void)n_in; (void)out_size; (void)ws_size;

    const float* query = (const float*)d_in[0];
    const float* key   = (const float*)d_in[1];
    const float* value = (const float*)d_in[2];
    const float* mask  = (const float*)d_in[3];
    const float* Wq    = (const float*)d_in[4];
    const float* bq    = (const float*)d_in[5];
    const float* Wk    = (const float*)d_in[6];
    const float* bk    = (const float*)d_in[7];
    const float* Wv    = (const float*)d_in[8];
    const float* bv    = (const float*)d_in[9];
    const float* Wo    = (const float*)d_in[10];
    const float* bo    = (const float*)d_in[11];
    float* out = (float*)d_out;

    float* ws = (float*)d_ws;
    const size_t per = (size_t)B_ * NH_ * S_ * HD_;   // 4194304 floats
    float* qh = ws;
    float* kh = ws + per;
    float* vh = ws + 2 * per;
    float* ao = ws + 3 * per;

    dim3 ggrid(8, 32);
    sgemm_kernel<1><<<ggrid, 256, 0, stream>>>(query, Wq, bq, qh, 0.125f);
    sgemm_kernel<1><<<ggrid, 256, 0, stream>>>(key,   Wk, bk, kh, 1.0f);
    sgemm_kernel<1><<<ggrid, 256, 0, stream>>>(value, Wv, bv, vh, 1.0f);

    dim3 agrid(S_ / 64, NH_, B_);
    attn_kernel<<<agrid, 256, 0, stream>>>(qh, kh, vh, mask, ao);

    sgemm_kernel<0><<<ggrid, 256, 0, stream>>>(ao, Wo, bo, out, 1.0f);
}

// Round 2
// 237.925 us; speedup vs baseline: 4.2194x; 4.2194x over previous
//
#include <hip/hip_runtime.h>
#include <math.h>

#define S_  2048
#define H_  1024
#define NH_ 16
#define HD_ 64
#define MM  4096            // B*S
#define NB_ 2               // batch

typedef __attribute__((ext_vector_type(8))) short bf16x8;
typedef __attribute__((ext_vector_type(4))) float f32x4;
typedef __attribute__((ext_vector_type(4))) unsigned short us4;
typedef __attribute__((ext_vector_type(8))) unsigned short us8;

__device__ __forceinline__ void gld_lds16(const void* g, void* l) {
    __builtin_amdgcn_global_load_lds(
        (const __attribute__((address_space(1))) unsigned int*)g,
        (__attribute__((address_space(3))) unsigned int*)l, 16, 0, 0);
}

__device__ __forceinline__ unsigned short f2bf(float f) {
    union { float f; unsigned int u; } v; v.f = f;
    unsigned int r = v.u + 0x7FFFu + ((v.u >> 16) & 1u);
    return (unsigned short)(r >> 16);
}

// ---------------------------------------------------------------------------
// fp32 -> bf16 elementwise convert (8 elems/thread)
// ---------------------------------------------------------------------------
__global__ __launch_bounds__(256)
void cvt_bf16(const float* __restrict__ s, unsigned short* __restrict__ d, int n8)
{
    int i = blockIdx.x * 256 + threadIdx.x;
    if (i >= n8) return;
    float4 a = ((const float4*)s)[i * 2];
    float4 b = ((const float4*)s)[i * 2 + 1];
    us8 o = { f2bf(a.x), f2bf(a.y), f2bf(a.z), f2bf(a.w),
              f2bf(b.x), f2bf(b.y), f2bf(b.z), f2bf(b.w) };
    ((us8*)d)[i] = o;
}

// ---------------------------------------------------------------------------
// W [K][N] fp32 -> Wt [N][K] bf16 (tiled transpose, 4 weights via blockIdx.z)
// ---------------------------------------------------------------------------
__global__ __launch_bounds__(256)
void wtr_kernel(const float* __restrict__ W0, const float* __restrict__ W1,
                const float* __restrict__ W2, const float* __restrict__ W3,
                unsigned short* __restrict__ T0, unsigned short* __restrict__ T1,
                unsigned short* __restrict__ T2, unsigned short* __restrict__ T3)
{
    __shared__ float t[32][33];
    const float* W = blockIdx.z == 0 ? W0 : blockIdx.z == 1 ? W1 : blockIdx.z == 2 ? W2 : W3;
    unsigned short* T = blockIdx.z == 0 ? T0 : blockIdx.z == 1 ? T1 : blockIdx.z == 2 ? T2 : T3;
    const int n0 = blockIdx.x * 32, k0 = blockIdx.y * 32;
    const int tx = threadIdx.x & 31, ty = threadIdx.x >> 5;   // ty 0..7
    #pragma unroll
    for (int u = 0; u < 4; u++)
        t[ty + u * 8][tx] = W[(size_t)(k0 + ty + u * 8) * H_ + n0 + tx];
    __syncthreads();
    #pragma unroll
    for (int u = 0; u < 4; u++)
        T[(size_t)(n0 + ty + u * 8) * H_ + k0 + tx] = f2bf(t[tx][ty + u * 8]);
}

// ---------------------------------------------------------------------------
// bf16 MFMA GEMM: C[m][n] = A[m][k] * Bt[n][k] (+bias, *scale)
// A: [4096][1024] bf16 row-major. Bt: [1024][1024] bf16 (B^T).
// Tile 128x128, BK=64, 256 thr / 4 waves (2x2), 4x4 frags of 16x16x32.
// LDS linear + 16B-block swizzle (blk ^= row&7) applied at the GLOBAL source
// (global_load_lds writes linearly) and undone at the ds_read side.
// EPI 0: head-split bf16 [B][NH][S][HD], value=(acc+bias)*scale
// EPI 1: transposed bf16 [B][NH][HD][S]  (for V)
// EPI 2: flat fp32 [M][N] + bias
// ---------------------------------------------------------------------------
template<int EPI>
__global__ __launch_bounds__(256)
void mfma_gemm(const unsigned short* __restrict__ A, const unsigned short* __restrict__ Bt,
               const float* __restrict__ bias, void* __restrict__ out, float scale)
{
    __shared__ __align__(16) unsigned short As[128 * 64];
    __shared__ __align__(16) unsigned short Bs[128 * 64];

    const int tid = threadIdx.x;
    const int lane = tid & 63, w = tid >> 6;
    const int lane16 = lane & 15, lg = lane >> 4;
    const int wm = w & 1, wn = w >> 1;
    const int n0 = blockIdx.x * 128, m0 = blockIdx.y * 128;

    f32x4 acc[4][4];
    #pragma unroll
    for (int m = 0; m < 4; m++)
        #pragma unroll
        for (int n = 0; n < 4; n++) acc[m][n] = (f32x4){0.f, 0.f, 0.f, 0.f};

    auto stage = [&](int kt) {
        #pragma unroll
        for (int u = 0; u < 4; u++) {
            const int seg = w * 4 + u;            // 0..15
            const int L = seg * 1024 + lane * 16; // LDS byte offset
            const int row = L >> 7;               // 0..127
            const int blk = (L >> 4) & 7;
            const int goff = kt * 64 + ((blk ^ (row & 7)) << 3);  // elements
            gld_lds16(A  + (size_t)(m0 + row) * 1024 + goff, (char*)As + L);
            gld_lds16(Bt + (size_t)(n0 + row) * 1024 + goff, (char*)Bs + L);
        }
    };

    stage(0);
    for (int kt = 0; kt < 16; kt++) {
        __syncthreads();   // staging complete (barrier drains vmcnt)
        #pragma unroll
        for (int ks = 0; ks < 2; ks++) {
            const int kb = ks * 64 + lg * 16;     // k byte offset within row
            bf16x8 a[4], b[4];
            #pragma unroll
            for (int m = 0; m < 4; m++) {
                const int row = wm * 64 + m * 16 + lane16;
                a[m] = *(const bf16x8*)((const char*)As + row * 128 + (kb ^ ((row & 7) << 4)));
            }
            #pragma unroll
            for (int n = 0; n < 4; n++) {
                const int row = wn * 64 + n * 16 + lane16;
                b[n] = *(const bf16x8*)((const char*)Bs + row * 128 + (kb ^ ((row & 7) << 4)));
            }
            #pragma unroll
            for (int m = 0; m < 4; m++)
                #pragma unroll
                for (int n = 0; n < 4; n++)
                    acc[m][n] = __builtin_amdgcn_mfma_f32_16x16x32_bf16(a[m], b[n], acc[m][n], 0, 0, 0);
        }
        __syncthreads();   // reads complete; safe to overwrite LDS
        if (kt + 1 < 16) stage(kt + 1);
    }

    #pragma unroll
    for (int n = 0; n < 4; n++) {
        const int col = n0 + wn * 64 + n * 16 + lane16;
        const float bs = bias[col];
        #pragma unroll
        for (int m = 0; m < 4; m++) {
            const int rowb = m0 + wm * 64 + m * 16 + lg * 4;
            if (EPI == 0) {
                const int nh = col >> 6, hd = col & 63;
                #pragma unroll
                for (int j = 0; j < 4; j++) {
                    const int row = rowb + j;
                    const int bb = row >> 11, s = row & 2047;
                    ((unsigned short*)out)[((((size_t)bb * NH_ + nh) * S_ + s) << 6) + hd] =
                        f2bf((acc[m][n][j] + bs) * scale);
                }
            } else if (EPI == 1) {
                const int nh = col >> 6, hd = col & 63;
                const int bb = rowb >> 11, s = rowb & 2047;
                us4 o;
                #pragma unroll
                for (int j = 0; j < 4; j++) o[j] = f2bf(acc[m][n][j] + bs);
                *(us4*)&((unsigned short*)out)[((((size_t)bb * NH_ + nh) * HD_ + hd) << 11) + s] = o;
            } else {
                #pragma unroll
                for (int j = 0; j < 4; j++)
                    ((float*)out)[(size_t)(rowb + j) * H_ + col] = acc[m][n][j] + bs;
            }
        }
    }
}

// ---------------------------------------------------------------------------
// bf16 MFMA flash attention.
// qh/kh: [B][NH][S][64] bf16 (q pre-scaled by 0.125). vt: [B][NH][64][S] bf16.
// mask: [B][S][S] fp32. ao: [B][S][H] bf16 (merged heads).
// Block: 256 thr / 4 waves; Q tile 64 rows (wave w owns rows w*16..+15);
// KV tiles of 64. 16x16x32 MFMA, online softmax in C-frag layout.
// ---------------------------------------------------------------------------
__global__ __launch_bounds__(256)
void mfma_attn(const unsigned short* __restrict__ qh, const unsigned short* __restrict__ kh,
               const unsigned short* __restrict__ vt, const float* __restrict__ mask,
               unsigned short* __restrict__ ao)
{
    __shared__ __align__(16) unsigned short Qs[64 * 64];
    __shared__ __align__(16) unsigned short Ks[64 * 64];
    __shared__ __align__(16) unsigned short Vs[64 * 64];   // [d][kv]
    __shared__ __align__(16) unsigned short St[64 * 72];   // [q][kv], padded

    const int tid = threadIdx.x;
    const int lane = tid & 63, w = tid >> 6;
    const int lane16 = lane & 15, lg = lane >> 4;
    const int qt = blockIdx.x, h = blockIdx.y, b = blockIdx.z;
    const int q0 = qt * 64;

    const unsigned short* Qb = qh + (((size_t)(b * NH_ + h) * S_) + q0) * HD_;
    const unsigned short* Kb = kh + ((size_t)(b * NH_ + h) * S_) * HD_;
    const unsigned short* Vb = vt + ((size_t)(b * NH_ + h) * HD_) * S_;
    const float* Mb = mask + ((size_t)b * S_ + q0) * S_;

    // stage Q (8 KB = 8 segs; wave w stages segs 2w, 2w+1)
    #pragma unroll
    for (int u = 0; u < 2; u++) {
        const int L = (w * 2 + u) * 1024 + lane * 16;
        const int row = L >> 7, blk = (L >> 4) & 7;
        gld_lds16(Qb + (size_t)row * HD_ + ((blk ^ (row & 7)) << 3), (char*)Qs + L);
    }
    auto stageK = [&](int t) {
        #pragma unroll
        for (int u = 0; u < 2; u++) {
            const int L = (w * 2 + u) * 1024 + lane * 16;
            const int row = L >> 7, blk = (L >> 4) & 7;
            gld_lds16(Kb + (size_t)(t * 64 + row) * HD_ + ((blk ^ (row & 7)) << 3), (char*)Ks + L);
        }
    };
    auto stageV = [&](int t) {
        #pragma unroll
        for (int u = 0; u < 2; u++) {
            const int L = (w * 2 + u) * 1024 + lane * 16;
            const int row = L >> 7, blk = (L >> 4) & 7;   // row = d
            gld_lds16(Vb + (size_t)row * S_ + t * 64 + ((blk ^ (row & 7)) << 3), (char*)Vs + L);
        }
    };
    stageK(0); stageV(0);

    f32x4 acc[4];
    float m_run[4], l_run[4];
    #pragma unroll
    for (int n = 0; n < 4; n++) acc[n] = (f32x4){0.f, 0.f, 0.f, 0.f};
    #pragma unroll
    for (int j = 0; j < 4; j++) { m_run[j] = -3.0e38f; l_run[j] = 0.f; }

    __syncthreads();   // Q/K0/V0 staged

    // hoist Q fragments (rows w*16+lane16, k contiguous)
    bf16x8 aq[2];
    #pragma unroll
    for (int ks = 0; ks < 2; ks++) {
        const int row = w * 16 + lane16;
        const int kb = ks * 64 + lg * 16;
        aq[ks] = *(const bf16x8*)((const char*)Qs + row * 128 + (kb ^ ((row & 7) << 4)));
    }

    for (int t = 0; t < S_ / 64; t++) {
        // ---- QK^T ----
        f32x4 sc[4];
        #pragma unroll
        for (int n = 0; n < 4; n++) sc[n] = (f32x4){0.f, 0.f, 0.f, 0.f};
        #pragma unroll
        for (int ks = 0; ks < 2; ks++) {
            const int kb = ks * 64 + lg * 16;
            #pragma unroll
            for (int n = 0; n < 4; n++) {
                const int row = n * 16 + lane16;   // kv pos
                bf16x8 bk = *(const bf16x8*)((const char*)Ks + row * 128 + (kb ^ ((row & 7) << 4)));
                sc[n] = __builtin_amdgcn_mfma_f32_16x16x32_bf16(aq[ks], bk, sc[n], 0, 0, 0);
            }
        }

        // ---- mask + online softmax (rows = w*16 + lg*4 + j) ----
        #pragma unroll
        for (int j = 0; j < 4; j++) {
            const int qr = w * 16 + lg * 4 + j;
            float v[4];
            #pragma unroll
            for (int n = 0; n < 4; n++)
                v[n] = sc[n][j] + Mb[(size_t)qr * S_ + t * 64 + n * 16 + lane16];
            float mx = fmaxf(fmaxf(v[0], v[1]), fmaxf(v[2], v[3]));
            mx = fmaxf(mx, __shfl_xor(mx, 1));
            mx = fmaxf(mx, __shfl_xor(mx, 2));
            mx = fmaxf(mx, __shfl_xor(mx, 4));
            mx = fmaxf(mx, __shfl_xor(mx, 8));
            const float mnew = fmaxf(m_run[j], mx);
            const float corr = __expf(m_run[j] - mnew);
            float ps = 0.f;
            #pragma unroll
            for (int n = 0; n < 4; n++) { v[n] = __expf(v[n] - mnew); ps += v[n]; }
            ps += __shfl_xor(ps, 1);
            ps += __shfl_xor(ps, 2);
            ps += __shfl_xor(ps, 4);
            ps += __shfl_xor(ps, 8);
            l_run[j] = l_run[j] * corr + ps;
            m_run[j] = mnew;
            #pragma unroll
            for (int n = 0; n < 4; n++) {
                acc[n][j] *= corr;
                St[qr * 72 + n * 16 + lane16] = f2bf(v[n]);
            }
        }
        __syncthreads();   // (B) QK reads of Ks done everywhere; St visible
        if (t + 1 < S_ / 64) stageK(t + 1);   // overlaps PV

        // ---- PV ----
        #pragma unroll
        for (int ks = 0; ks < 2; ks++) {
            bf16x8 pa = *(const bf16x8*)((const char*)St + (w * 16 + lane16) * 144 + ks * 64 + lg * 16);
            #pragma unroll
            for (int n = 0; n < 4; n++) {
                const int row = n * 16 + lane16;   // d
                const int kb = ks * 64 + lg * 16;  // kv bytes
                bf16x8 vb = *(const bf16x8*)((const char*)Vs + row * 128 + (kb ^ ((row & 7) << 4)));
                acc[n] = __builtin_amdgcn_mfma_f32_16x16x32_bf16(pa, vb, acc[n], 0, 0, 0);
            }
        }
        __syncthreads();   // (C) PV reads of Vs done; K staging drained
        if (t + 1 < S_ / 64) stageV(t + 1);
    }

    // epilogue
    #pragma unroll
    for (int j = 0; j < 4; j++) {
        const float inv = 1.0f / l_run[j];
        const int qr = q0 + w * 16 + lg * 4 + j;
        #pragma unroll
        for (int n = 0; n < 4; n++)
            ao[((size_t)(b * S_ + qr)) * H_ + h * HD_ + n * 16 + lane16] = f2bf(acc[n][j] * inv);
    }
}

// ---------------------------------------------------------------------------
extern "C" void kernel_launch(void* const* d_in, const int* in_sizes, int n_in,
                              void* d_out, int out_size, void* d_ws, size_t ws_size,
                              hipStream_t stream)
{
    (void)in_sizes; (void)n_in; (void)out_size; (void)ws_size;

    const float* query = (const float*)d_in[0];
    const float* key   = (const float*)d_in[1];
    const float* value = (const float*)d_in[2];
    const float* mask  = (const float*)d_in[3];
    const float* Wq    = (const float*)d_in[4];
    const float* bq    = (const float*)d_in[5];
    const float* Wk    = (const float*)d_in[6];
    const float* bk    = (const float*)d_in[7];
    const float* Wv    = (const float*)d_in[8];
    const float* bv    = (const float*)d_in[9];
    const float* Wo    = (const float*)d_in[10];
    const float* bo    = (const float*)d_in[11];

    unsigned short* ws = (unsigned short*)d_ws;
    const size_t MH = (size_t)MM * H_;       // 4 Mi elems
    const size_t WW = (size_t)H_ * H_;       // 1 Mi elems
    unsigned short* Xq  = ws;
    unsigned short* Xk  = Xq + MH;
    unsigned short* Xv  = Xk + MH;
    unsigned short* Wtq = Xv + MH;
    unsigned short* Wtk = Wtq + WW;
    unsigned short* Wtv = Wtk + WW;
    unsigned short* Wto = Wtv + WW;
    unsigned short* qh  = Wto + WW;
    unsigned short* kh  = qh + MH;
    unsigned short* vt  = kh + MH;
    unsigned short* ao  = vt + MH;

    const int n8 = (int)(MH / 8);            // 524288
    cvt_bf16<<<n8 / 256, 256, 0, stream>>>(query, Xq, n8);
    cvt_bf16<<<n8 / 256, 256, 0, stream>>>(key,   Xk, n8);
    cvt_bf16<<<n8 / 256, 256, 0, stream>>>(value, Xv, n8);
    wtr_kernel<<<dim3(32, 32, 4), 256, 0, stream>>>(Wq, Wk, Wv, Wo, Wtq, Wtk, Wtv, Wto);

    dim3 gg(8, 32);   // N/128, M/128
    mfma_gemm<0><<<gg, 256, 0, stream>>>(Xq, Wtq, bq, qh, 0.125f);
    mfma_gemm<0><<<gg, 256, 0, stream>>>(Xk, Wtk, bk, kh, 1.0f);
    mfma_gemm<1><<<gg, 256, 0, stream>>>(Xv, Wtv, bv, vt, 1.0f);

    mfma_attn<<<dim3(S_ / 64, NH_, NB_), 256, 0, stream>>>(qh, kh, vt, mask, ao);

    mfma_gemm<2><<<gg, 256, 0, stream>>>(ao, Wto, bo, d_out, 1.0f);
}

// Round 5
// 196.918 us; speedup vs baseline: 5.0980x; 1.2082x over previous
//
#include <hip/hip_runtime.h>
#include <math.h>

#define S_  2048
#define H_  1024
#define NH_ 16
#define HD_ 64
#define MM  4096            // B*S
#define NB_ 2               // batch
#define LOG2E 1.44269504088896340736f

typedef __attribute__((ext_vector_type(8))) short bf16x8;
typedef __attribute__((ext_vector_type(4))) float f32x4;
typedef __attribute__((ext_vector_type(16))) float f32x16;
typedef __attribute__((ext_vector_type(4))) unsigned short us4;
typedef __attribute__((ext_vector_type(8))) unsigned short us8;

__device__ __forceinline__ void gld_lds16(const void* g, void* l) {
    __builtin_amdgcn_global_load_lds(
        (const __attribute__((address_space(1))) unsigned int*)g,
        (__attribute__((address_space(3))) unsigned int*)l, 16, 0, 0);
}

__device__ __forceinline__ unsigned short f2bf(float f) {
    union { float f; unsigned int u; } v; v.f = f;
    unsigned int r = v.u + 0x7FFFu + ((v.u >> 16) & 1u);
    return (unsigned short)(r >> 16);
}

__device__ __forceinline__ float exp2_fast(float x) {
    float r; asm("v_exp_f32 %0, %1" : "=v"(r) : "v"(x)); return r;
}

// ---------------------------------------------------------------------------
// fp32 -> bf16 elementwise convert (8 elems/thread)
// ---------------------------------------------------------------------------
__global__ __launch_bounds__(256)
void cvt_bf16(const float* __restrict__ s, unsigned short* __restrict__ d, int n8)
{
    int i = blockIdx.x * 256 + threadIdx.x;
    if (i >= n8) return;
    float4 a = ((const float4*)s)[i * 2];
    float4 b = ((const float4*)s)[i * 2 + 1];
    us8 o = { f2bf(a.x), f2bf(a.y), f2bf(a.z), f2bf(a.w),
              f2bf(b.x), f2bf(b.y), f2bf(b.z), f2bf(b.w) };
    ((us8*)d)[i] = o;
}

// ---------------------------------------------------------------------------
// W [K][N] fp32 -> Wt [N][K] bf16 (tiled transpose, 4 weights via blockIdx.z)
// ---------------------------------------------------------------------------
__global__ __launch_bounds__(256)
void wtr_kernel(const float* __restrict__ W0, const float* __restrict__ W1,
                const float* __restrict__ W2, const float* __restrict__ W3,
                unsigned short* __restrict__ T0, unsigned short* __restrict__ T1,
                unsigned short* __restrict__ T2, unsigned short* __restrict__ T3)
{
    __shared__ float t[32][33];
    const float* W = blockIdx.z == 0 ? W0 : blockIdx.z == 1 ? W1 : blockIdx.z == 2 ? W2 : W3;
    unsigned short* T = blockIdx.z == 0 ? T0 : blockIdx.z == 1 ? T1 : blockIdx.z == 2 ? T2 : T3;
    const int n0 = blockIdx.x * 32, k0 = blockIdx.y * 32;
    const int tx = threadIdx.x & 31, ty = threadIdx.x >> 5;   // ty 0..7
    #pragma unroll
    for (int u = 0; u < 4; u++)
        t[ty + u * 8][tx] = W[(size_t)(k0 + ty + u * 8) * H_ + n0 + tx];
    __syncthreads();
    #pragma unroll
    for (int u = 0; u < 4; u++)
        T[(size_t)(n0 + ty + u * 8) * H_ + k0 + tx] = f2bf(t[tx][ty + u * 8]);
}

// ---------------------------------------------------------------------------
// bf16 MFMA GEMM (m97 structure), unchanged.
// EPI 0: head-split bf16 [B][NH][S][HD], value=(acc+bias)*scale
// EPI 1: transposed bf16 [B][NH][HD][S]  (for V)
// EPI 2: flat fp32 [M][N] + bias
// ---------------------------------------------------------------------------
template<int EPI>
__global__ __launch_bounds__(256)
void mfma_gemm(const unsigned short* __restrict__ A, const unsigned short* __restrict__ Bt,
               const float* __restrict__ bias, void* __restrict__ out, float scale)
{
    __shared__ __align__(16) unsigned short As[128 * 64];
    __shared__ __align__(16) unsigned short Bs[128 * 64];

    const int tid = threadIdx.x;
    const int lane = tid & 63, w = tid >> 6;
    const int lane16 = lane & 15, lg = lane >> 4;
    const int wm = w & 1, wn = w >> 1;
    const int n0 = blockIdx.x * 128, m0 = blockIdx.y * 128;

    f32x4 acc[4][4];
    #pragma unroll
    for (int m = 0; m < 4; m++)
        #pragma unroll
        for (int n = 0; n < 4; n++) acc[m][n] = (f32x4){0.f, 0.f, 0.f, 0.f};

    auto stage = [&](int kt) {
        #pragma unroll
        for (int u = 0; u < 4; u++) {
            const int seg = w * 4 + u;            // 0..15
            const int L = seg * 1024 + lane * 16; // LDS byte offset
            const int row = L >> 7;               // 0..127
            const int blk = (L >> 4) & 7;
            const int goff = kt * 64 + ((blk ^ (row & 7)) << 3);  // elements
            gld_lds16(A  + (size_t)(m0 + row) * 1024 + goff, (char*)As + L);
            gld_lds16(Bt + (size_t)(n0 + row) * 1024 + goff, (char*)Bs + L);
        }
    };

    stage(0);
    for (int kt = 0; kt < 16; kt++) {
        __syncthreads();
        #pragma unroll
        for (int ks = 0; ks < 2; ks++) {
            const int kb = ks * 64 + lg * 16;     // k byte offset within row
            bf16x8 a[4], b[4];
            #pragma unroll
            for (int m = 0; m < 4; m++) {
                const int row = wm * 64 + m * 16 + lane16;
                a[m] = *(const bf16x8*)((const char*)As + row * 128 + (kb ^ ((row & 7) << 4)));
            }
            #pragma unroll
            for (int n = 0; n < 4; n++) {
                const int row = wn * 64 + n * 16 + lane16;
                b[n] = *(const bf16x8*)((const char*)Bs + row * 128 + (kb ^ ((row & 7) << 4)));
            }
            #pragma unroll
            for (int m = 0; m < 4; m++)
                #pragma unroll
                for (int n = 0; n < 4; n++)
                    acc[m][n] = __builtin_amdgcn_mfma_f32_16x16x32_bf16(a[m], b[n], acc[m][n], 0, 0, 0);
        }
        __syncthreads();
        if (kt + 1 < 16) stage(kt + 1);
    }

    #pragma unroll
    for (int n = 0; n < 4; n++) {
        const int col = n0 + wn * 64 + n * 16 + lane16;
        const float bs = bias[col];
        #pragma unroll
        for (int m = 0; m < 4; m++) {
            const int rowb = m0 + wm * 64 + m * 16 + lg * 4;
            if (EPI == 0) {
                const int nh = col >> 6, hd = col & 63;
                #pragma unroll
                for (int j = 0; j < 4; j++) {
                    const int row = rowb + j;
                    const int bb = row >> 11, s = row & 2047;
                    ((unsigned short*)out)[((((size_t)bb * NH_ + nh) * S_ + s) << 6) + hd] =
                        f2bf((acc[m][n][j] + bs) * scale);
                }
            } else if (EPI == 1) {
                const int nh = col >> 6, hd = col & 63;
                const int bb = rowb >> 11, s = rowb & 2047;
                us4 o;
                #pragma unroll
                for (int j = 0; j < 4; j++) o[j] = f2bf(acc[m][n][j] + bs);
                *(us4*)&((unsigned short*)out)[((((size_t)bb * NH_ + nh) * HD_ + hd) << 11) + s] = o;
            } else {
                #pragma unroll
                for (int j = 0; j < 4; j++)
                    ((float*)out)[(size_t)(rowb + j) * H_ + col] = acc[m][n][j] + bs;
            }
        }
    }
}

// ---------------------------------------------------------------------------
// bf16 MFMA flash attention, swapped-QK^T + in-register softmax.
// qh: [B][NH][S][64] bf16, pre-scaled by 0.125*log2(e). kh: same layout.
// vt: [B][NH][64][S] bf16 (V^T). mask: [B][S][S] fp32. ao: [B][S][H] bf16.
// Block: 4 waves x 32 q-rows = 128-q tile; KV tiles of 64; 32x32x16 MFMA.
// S^T = mfma(K, Q-frags): lane owns q = lane&31; kv = (r&3)+8*(r>>2)+4*lg2.
// P^T goes through a wave-private LDS buffer (pi-invariant both-side
// contiguous slot addressing); cross-half exchanges via __shfl_xor(.,32).
// ---------------------------------------------------------------------------
__global__ __launch_bounds__(256, 2)
void mfma_attn(const unsigned short* __restrict__ qh, const unsigned short* __restrict__ kh,
               const unsigned short* __restrict__ vt, const float* __restrict__ mask,
               unsigned short* __restrict__ ao)
{
    __shared__ __align__(16) unsigned short Qs[128 * 64];
    __shared__ __align__(16) unsigned short Ks[2][64 * 64];
    __shared__ __align__(16) unsigned short Vs[2][64 * 64];   // [d][kv]
    __shared__ __align__(16) unsigned short St[128 * 64];     // [q][kv] (wave-private rows)

    const int tid = threadIdx.x;
    const int lane = tid & 63, wq = tid >> 6;
    const int l31 = lane & 31, lg2 = lane >> 5;
    const int qt = blockIdx.x, h = blockIdx.y, bz = blockIdx.z;
    const int q0 = qt * 128;

    const unsigned short* Qb = qh + (((size_t)(bz * NH_ + h) * S_) + q0) * HD_;
    const unsigned short* Kb = kh + ((size_t)(bz * NH_ + h) * S_) * HD_;
    const unsigned short* Vb = vt + ((size_t)(bz * NH_ + h) * HD_) * S_;
    const int qrow = wq * 32 + l31;                   // tile-local q row
    const int q = q0 + qrow;                          // global q row
    const float* Mlane = mask + ((size_t)bz * S_ + q) * S_;

    // ---- stage Q (16 KB = 4 passes of 256 thr x 16 B) ----
    #pragma unroll
    for (int u = 0; u < 4; u++) {
        const int L = u * 4096 + tid * 16;
        const int row = L >> 7, blk = (L >> 4) & 7;
        gld_lds16(Qb + (size_t)row * HD_ + ((blk ^ (row & 7)) << 3), (char*)Qs + L);
    }
    // ---- K/V tile staging (8 KB each = 2 passes each) ----
    auto stageKV = [&](int t) {
        const int buf = t & 1;
        #pragma unroll
        for (int u = 0; u < 2; u++) {
            const int L = u * 4096 + tid * 16;
            const int row = L >> 7, blk = (L >> 4) & 7;   // row: kv for K, d for V
            const int off = (blk ^ (row & 7)) << 3;
            gld_lds16(Kb + (size_t)(t * 64 + row) * HD_ + off, (char*)&Ks[buf][0] + L);
            gld_lds16(Vb + (size_t)row * S_ + t * 64 + off,    (char*)&Vs[buf][0] + L);
        }
    };
    stageKV(0);
    __syncthreads();

    // ---- hoist Q fragments (B-operand: col q=l31, k=d contiguous 8) ----
    bf16x8 qfrag[4];
    #pragma unroll
    for (int s = 0; s < 4; s++)
        qfrag[s] = *(const bf16x8*)((const char*)Qs + qrow * 128 +
                                    ((s * 32 + lg2 * 16) ^ ((qrow & 7) << 4)));

    f32x16 oacc[2];
    #pragma unroll
    for (int db = 0; db < 2; db++)
        #pragma unroll
        for (int i = 0; i < 16; i++) oacc[db][i] = 0.f;
    float m_run = -3.0e38f, l_run = 0.f;

    for (int t = 0; t < S_ / 64; t++) {
        if (t) __syncthreads();        // K/V(t) staged; all waves done with buf^1
        const int buf = t & 1;

        // ---- mask loads (issued early; consumed after QK) ----
        float4 mreg[2][4];
        #pragma unroll
        for (int bb = 0; bb < 2; bb++)
            #pragma unroll
            for (int m = 0; m < 4; m++)
                mreg[bb][m] = *(const float4*)(Mlane + t * 64 + bb * 32 + m * 8 + lg2 * 4);

        // ---- prefetch next K/V ----
        if (t + 1 < S_ / 64) stageKV(t + 1);

        // ---- QK^T (S^T[kv][q]) ----
        f32x16 sc[2];
        #pragma unroll
        for (int bb = 0; bb < 2; bb++) {
            f32x16 a;
            #pragma unroll
            for (int i = 0; i < 16; i++) a[i] = 0.f;
            #pragma unroll
            for (int s = 0; s < 4; s++) {
                const int row = bb * 32 + l31;
                bf16x8 kf = *(const bf16x8*)((const char*)&Ks[buf][0] + row * 128 +
                                             ((s * 32 + lg2 * 16) ^ ((row & 7) << 4)));
                a = __builtin_amdgcn_mfma_f32_32x32x16_bf16(kf, qfrag[s], a, 0, 0, 0);
            }
            sc[bb] = a;
        }

        // ---- mask add (base-2 domain) ----
        #pragma unroll
        for (int bb = 0; bb < 2; bb++)
            #pragma unroll
            for (int m = 0; m < 4; m++) {
                sc[bb][m * 4 + 0] = fmaf(mreg[bb][m].x, LOG2E, sc[bb][m * 4 + 0]);
                sc[bb][m * 4 + 1] = fmaf(mreg[bb][m].y, LOG2E, sc[bb][m * 4 + 1]);
                sc[bb][m * 4 + 2] = fmaf(mreg[bb][m].z, LOG2E, sc[bb][m * 4 + 2]);
                sc[bb][m * 4 + 3] = fmaf(mreg[bb][m].w, LOG2E, sc[bb][m * 4 + 3]);
            }

        // ---- row max (in-register tree + cross-half via shfl) ----
        float t8[8];
        #pragma unroll
        for (int i = 0; i < 8; i++)
            t8[i] = fmaxf(fmaxf(sc[0][i], sc[0][i + 8]), fmaxf(sc[1][i], sc[1][i + 8]));
        float mloc = fmaxf(fmaxf(fmaxf(t8[0], t8[1]), fmaxf(t8[2], t8[3])),
                           fmaxf(fmaxf(t8[4], t8[5]), fmaxf(t8[6], t8[7])));
        const float mtile = fmaxf(mloc, __shfl_xor(mloc, 32, 64));

        // ---- defer-max (T13): skip rescale when growth <= 8 (base-2) ----
        float mnew;
        if (__all(mtile <= m_run + 8.f)) {
            mnew = m_run;
        } else {
            mnew = fmaxf(m_run, mtile);
            const float corr = exp2_fast(m_run - mnew);
            l_run *= corr;
            #pragma unroll
            for (int db = 0; db < 2; db++)
                #pragma unroll
                for (int i = 0; i < 16; i++) oacc[db][i] *= corr;
        }
        m_run = mnew;

        // ---- exp + row sum ----
        #pragma unroll
        for (int bb = 0; bb < 2; bb++)
            #pragma unroll
            for (int i = 0; i < 16; i++)
                sc[bb][i] = exp2_fast(sc[bb][i] - mnew);
        float s8[8];
        #pragma unroll
        for (int i = 0; i < 8; i++)
            s8[i] = (sc[0][i] + sc[0][i + 8]) + (sc[1][i] + sc[1][i + 8]);
        float sloc = ((s8[0] + s8[1]) + (s8[2] + s8[3])) + ((s8[4] + s8[5]) + (s8[6] + s8[7]));
        l_run += sloc + __shfl_xor(sloc, 32, 64);

        // ---- P^T -> LDS (wave-private rows; pairs of consecutive kv) ----
        #pragma unroll
        for (int bb = 0; bb < 2; bb++)
            #pragma unroll
            for (int r = 0; r < 16; r += 2) {
                const unsigned pv = (unsigned)f2bf(sc[bb][r]) |
                                    ((unsigned)f2bf(sc[bb][r + 1]) << 16);
                const int kvb = bb * 64 + 2 * (r & 3) + 16 * (r >> 2) + 8 * lg2;  // byte
                *(unsigned*)((char*)St + qrow * 128 + (kvb ^ ((qrow & 7) << 4))) = pv;
            }

        // ---- read P^T B-frags (same contiguous slot addressing as V) ----
        bf16x8 pfrag[4];
        #pragma unroll
        for (int s = 0; s < 4; s++)
            pfrag[s] = *(const bf16x8*)((const char*)St + qrow * 128 +
                                        ((s * 32 + lg2 * 16) ^ ((qrow & 7) << 4)));

        // ---- PV: O^T[d][q] += V^T-frag x P^T-frag ----
        #pragma unroll
        for (int s = 0; s < 4; s++)
            #pragma unroll
            for (int db = 0; db < 2; db++) {
                const int row = db * 32 + l31;
                bf16x8 vf = *(const bf16x8*)((const char*)&Vs[buf][0] + row * 128 +
                                             ((s * 32 + lg2 * 16) ^ ((row & 7) << 4)));
                oacc[db] = __builtin_amdgcn_mfma_f32_32x32x16_bf16(vf, pfrag[s], oacc[db], 0, 0, 0);
            }
    }

    // ---- epilogue: O[q][d] = O^T/l ----
    const float inv = 1.0f / l_run;
    unsigned short* aoq = ao + ((size_t)(bz * S_ + q)) * H_ + h * HD_;
    #pragma unroll
    for (int db = 0; db < 2; db++)
        #pragma unroll
        for (int m = 0; m < 4; m++) {
            us4 o = { f2bf(oacc[db][m * 4 + 0] * inv), f2bf(oacc[db][m * 4 + 1] * inv),
                      f2bf(oacc[db][m * 4 + 2] * inv), f2bf(oacc[db][m * 4 + 3] * inv) };
            *(us4*)&aoq[db * 32 + m * 8 + lg2 * 4] = o;
        }
}

// ---------------------------------------------------------------------------
extern "C" void kernel_launch(void* const* d_in, const int* in_sizes, int n_in,
                              void* d_out, int out_size, void* d_ws, size_t ws_size,
                              hipStream_t stream)
{
    (void)in_sizes; (void)n_in; (void)out_size; (void)ws_size;

    const float* query = (const float*)d_in[0];
    const float* key   = (const float*)d_in[1];
    const float* value = (const float*)d_in[2];
    const float* mask  = (const float*)d_in[3];
    const float* Wq    = (const float*)d_in[4];
    const float* bq    = (const float*)d_in[5];
    const float* Wk    = (const float*)d_in[6];
    const float* bk    = (const float*)d_in[7];
    const float* Wv    = (const float*)d_in[8];
    const float* bv    = (const float*)d_in[9];
    const float* Wo    = (const float*)d_in[10];
    const float* bo    = (const float*)d_in[11];

    unsigned short* ws = (unsigned short*)d_ws;
    const size_t MH = (size_t)MM * H_;       // 4 Mi elems
    const size_t WW = (size_t)H_ * H_;       // 1 Mi elems
    unsigned short* Xq  = ws;
    unsigned short* Xk  = Xq + MH;
    unsigned short* Xv  = Xk + MH;
    unsigned short* Wtq = Xv + MH;
    unsigned short* Wtk = Wtq + WW;
    unsigned short* Wtv = Wtk + WW;
    unsigned short* Wto = Wtv + WW;
    unsigned short* qh  = Wto + WW;
    unsigned short* kh  = qh + MH;
    unsigned short* vt  = kh + MH;
    unsigned short* ao  = vt + MH;

    const int n8 = (int)(MH / 8);            // 524288
    cvt_bf16<<<n8 / 256, 256, 0, stream>>>(query, Xq, n8);
    cvt_bf16<<<n8 / 256, 256, 0, stream>>>(key,   Xk, n8);
    cvt_bf16<<<n8 / 256, 256, 0, stream>>>(value, Xv, n8);
    wtr_kernel<<<dim3(32, 32, 4), 256, 0, stream>>>(Wq, Wk, Wv, Wo, Wtq, Wtk, Wtv, Wto);

    dim3 gg(8, 32);   // N/128, M/128
    mfma_gemm<0><<<gg, 256, 0, stream>>>(Xq, Wtq, bq, qh, 0.125f * LOG2E);
    mfma_gemm<0><<<gg, 256, 0, stream>>>(Xk, Wtk, bk, kh, 1.0f);
    mfma_gemm<1><<<gg, 256, 0, stream>>>(Xv, Wtv, bv, vt, 1.0f);

    mfma_attn<<<dim3(S_ / 128, NH_, NB_), 256, 0, stream>>>(qh, kh, vt, mask, ao);

    mfma_gemm<2><<<gg, 256, 0, stream>>>(ao, Wto, bo, d_out, 1.0f);
}